// Round 7
// baseline (419.520 us; speedup 1.0000x reference)
//
#include <hip/hip_runtime.h>
#include <hip/hip_bf16.h>

typedef short bf16x8 __attribute__((ext_vector_type(8)));
typedef float f32x4  __attribute__((ext_vector_type(4)));

#define T_SEQ 4096
#define NB    4
#define E_DIM 2048
#define D_DIM 128
#define M_TOT (NB * T_SEQ)  // 16384
#define SM_SHIFT 12.0f

__device__ __forceinline__ ushort f2bf(float f) {
  union { float f; unsigned u; } c; c.f = f;
  unsigned u = c.u;
  unsigned r = (u + 0x7FFFu + ((u >> 16) & 1u)) >> 16;  // RNE
  return (ushort)r;
}
__device__ __forceinline__ float bf2f(ushort u) {
  union { unsigned u; float f; } c; c.u = ((unsigned)u) << 16;
  return c.f;
}
// 8 fp32 -> bf16x8 via packed RNE converts
__device__ __forceinline__ bf16x8 cvt8(const float4& lo, const float4& hi) {
  union { __hip_bfloat162 h; ushort u[2]; } t;
  union { ushort u[8]; bf16x8 v; } r;
  t.h = __float22bfloat162_rn(make_float2(lo.x, lo.y)); r.u[0] = t.u[0]; r.u[1] = t.u[1];
  t.h = __float22bfloat162_rn(make_float2(lo.z, lo.w)); r.u[2] = t.u[0]; r.u[3] = t.u[1];
  t.h = __float22bfloat162_rn(make_float2(hi.x, hi.y)); r.u[4] = t.u[0]; r.u[5] = t.u[1];
  t.h = __float22bfloat162_rn(make_float2(hi.z, hi.w)); r.u[6] = t.u[0]; r.u[7] = t.u[1];
  return r.v;
}
__device__ __forceinline__ bf16x8 ld_frag(const ushort* p) {
  union { uint4 q; bf16x8 v; } u;
  u.q = *(const uint4*)p;
  return u.v;
}

// ============ kernel 1: W [k][n] fp32 -> Wtp MFMA-B-fragment-packed bf16 ============
// fragment (nt over N=384/16, kt over K=2048/32): 64 lanes x 16B; lane(l16,quad)
// holds B[n = nt*16+l16][k = kt*32+quad*8 .. +8].  Wtp elem offset = (nt*64+kt)*512 + lane*8.
__global__ __launch_bounds__(256) void build_wtp(const float* __restrict__ Wq,
                                                 const float* __restrict__ Wk,
                                                 const float* __restrict__ Wv,
                                                 ushort* __restrict__ Wtp) {
  __shared__ ushort tile[64][72];   // [k-local][n-local]
  const int tid = threadIdx.x;
  const int wave = tid >> 6, lane = tid & 63;
  const int quad = lane >> 4, l16 = lane & 15;
  const int k0 = blockIdx.x * 64, nl0 = blockIdx.y * 64, o = blockIdx.z;
  const float* W = (o == 0) ? Wq : ((o == 1) ? Wk : Wv);
  for (int i = 0; i < 4; i++) {
    int c = tid + i * 256;
    int r = c >> 4, c4 = (c & 15) * 4;
    float4 v = *(const float4*)(W + (size_t)(k0 + r) * D_DIM + nl0 + c4);
    ushort4 b4;
    b4.x = f2bf(v.x); b4.y = f2bf(v.y); b4.z = f2bf(v.z); b4.w = f2bf(v.w);
    *(ushort4*)(&tile[r][c4]) = b4;
  }
  __syncthreads();
  // 8 frags (4 nt-local x 2 kt-local); wave w -> frags w*2, w*2+1
  for (int j = 0; j < 2; j++) {
    int f = wave * 2 + j;
    int ntl = f >> 1, ktl = f & 1;
    ushort tmp[8];
    for (int jj = 0; jj < 8; jj++) tmp[jj] = tile[ktl * 32 + quad * 8 + jj][ntl * 16 + l16];
    int ntg = o * 8 + (nl0 >> 4) + ntl;
    int ktg = (k0 >> 5) + ktl;
    *(uint4*)(Wtp + (size_t)(ntg * 64 + ktg) * 512 + lane * 8) = *(const uint4*)tmp;
  }
}

// ============ kernel 2: QKV GEMM, barrier-free, zero-LDS ============
// grid (256,2), 4 waves 2x2; wave tile 32(M) x 96(N); K-step 32 (one fragment).
// B from Wtp: coalesced 1KB fragment loads (L2-resident). A direct from x fp32
// (16-row pattern, each 128B line fully consumed) + packed cvt. No __syncthreads.
__global__ __launch_bounds__(256) void qkv_gemm(const float* __restrict__ x,
                                                const ushort* __restrict__ Wtp,
                                                ushort* __restrict__ Q,
                                                ushort* __restrict__ K,
                                                ushort* __restrict__ V) {
  const int tid  = threadIdx.x;
  const int wave = tid >> 6, lane = tid & 63;
  const int quad = lane >> 4, l16 = lane & 15;
  const int wm = wave >> 1, wn = wave & 1;
  const int m0 = blockIdx.x * 64;
  const int n0 = blockIdx.y * 192;

  f32x4 acc[2][6] = {};

  const float* xb0 = x + (size_t)(m0 + wm * 32 + l16) * E_DIM + quad * 8;
  const float* xb1 = xb0 + (size_t)16 * E_DIM;
  const int ntbase = (n0 >> 4) + wn * 6;  // B fragment nt base

  for (int kt = 0; kt < 64; kt++) {
    // A fragments (fp32 direct + cvt)
    float4 a0l = *(const float4*)(xb0 + kt * 32);
    float4 a0h = *(const float4*)(xb0 + kt * 32 + 4);
    float4 a1l = *(const float4*)(xb1 + kt * 32);
    float4 a1h = *(const float4*)(xb1 + kt * 32 + 4);
    // B fragments (coalesced 1KB each)
    bf16x8 bf[6];
#pragma unroll
    for (int ni = 0; ni < 6; ni++)
      bf[ni] = ld_frag(Wtp + (size_t)((ntbase + ni) * 64 + kt) * 512 + lane * 8);
    bf16x8 af0 = cvt8(a0l, a0h);
    bf16x8 af1 = cvt8(a1l, a1h);
#pragma unroll
    for (int ni = 0; ni < 6; ni++) {
      acc[0][ni] = __builtin_amdgcn_mfma_f32_16x16x32_bf16(af0, bf[ni], acc[0][ni], 0, 0, 0);
      acc[1][ni] = __builtin_amdgcn_mfma_f32_16x16x32_bf16(af1, bf[ni], acc[1][ni], 0, 0, 0);
    }
  }

  for (int mi = 0; mi < 2; mi++)
    for (int ni = 0; ni < 6; ni++) {
      int colall = n0 + wn * 96 + ni * 16 + l16;
      int o = colall >> 7, d = colall & 127;
      ushort* dst = (o == 0) ? Q : ((o == 1) ? K : V);
      for (int r = 0; r < 4; r++) {
        int row = m0 + wm * 32 + mi * 16 + quad * 4 + r;
        dst[(size_t)row * D_DIM + d] = f2bf(acc[mi][ni][r]);
      }
    }
}

// ============ kernel 3: K [b][t][d] -> Kp QK-B-fragment-packed ============
// fragment (b, nt = t/16, kt = d/32): lane holds K[b][nt*16+l16][kt*32+quad*8..+8]
// Kp offset = ((b*256 + nt)*4 + kt)*512 + lane*8.   grid (64, NB)
__global__ __launch_bounds__(256) void k_pack(const ushort* __restrict__ K,
                                              ushort* __restrict__ Kp) {
  const int tid = threadIdx.x;
  const int wave = tid >> 6, lane = tid & 63;
  const int quad = lane >> 4, l16 = lane & 15;
  const int t0 = blockIdx.x * 64, b = blockIdx.y;
  for (int j = 0; j < 4; j++) {
    int f = wave * 4 + j;          // 16 frags: ntl = f>>2, ktd = f&3
    int ntl = f >> 2, ktd = f & 3;
    uint4 v = *(const uint4*)(K + (size_t)(b * T_SEQ + t0 + ntl * 16 + l16) * D_DIM + ktd * 32 + quad * 8);
    *(uint4*)(Kp + (size_t)(((b * 256 + (t0 >> 4) + ntl) * 4) + ktd) * 512 + lane * 8) = v;
  }
}

// ============ kernel 4: V [b][t][d] -> Vp PV-B-fragment-packed (transposed) ============
// fragment (b, nt = d/16, kt = t/32): lane holds V[b][kt*32+quad*8+j][nt*16+l16], j=0..7
// Vp offset = ((b*8 + nt)*128 + kt)*512 + lane*8.   grid (64, NB)
__global__ __launch_bounds__(256) void v_pack(const ushort* __restrict__ V,
                                              ushort* __restrict__ Vp) {
  __shared__ ushort tile[64][136];   // [t-local][d]
  const int tid = threadIdx.x;
  const int wave = tid >> 6, lane = tid & 63;
  const int quad = lane >> 4, l16 = lane & 15;
  const int t0 = blockIdx.x * 64, b = blockIdx.y;
  for (int i = 0; i < 4; i++) {
    int c = tid + i * 256;
    int r = c >> 4, cc = (c & 15) * 8;
    *(uint4*)(&tile[r][cc]) = *(const uint4*)(V + (size_t)(b * T_SEQ + t0 + r) * D_DIM + cc);
  }
  __syncthreads();
  for (int j = 0; j < 4; j++) {
    int f = wave * 4 + j;          // 16 frags: ntd = f>>1 (0..7), ktt = f&1
    int ntd = f >> 1, ktt = f & 1;
    ushort tmp[8];
    for (int jj = 0; jj < 8; jj++) tmp[jj] = tile[ktt * 32 + quad * 8 + jj][ntd * 16 + l16];
    *(uint4*)(Vp + (size_t)((b * 8 + ntd) * 128 + (t0 >> 5) + ktt) * 512 + lane * 8) = *(const uint4*)tmp;
  }
}

// ============ kernel 5: flash attention partial — barrier-free, fragment loads ============
// grid (qt=32, cq=nchunk, b=4); block 4 waves, BM=128 (32 q-rows/wave, mi 0..1);
// per 64-kv tile: QK (16 coalesced Kp frags), fixed-shift exp2, P via per-wave LDS
// (C->A layout), PV (16 coalesced Vp frags) + row-sum MFMA vs ones. No __syncthreads.
__global__ void attn_partial(const ushort* __restrict__ Q,
                             const ushort* __restrict__ Kp,
                             const ushort* __restrict__ Vp,
                             ushort* __restrict__ Po,
                             float* __restrict__ Ll,
                             int chunkKT, int nchunk) {
  const int qt = blockIdx.x, cq = blockIdx.y, b = blockIdx.z;
  const int ktmax = qt * 2 + 1;            // last kv tile needed
  const int kt0 = cq * chunkKT;
  if (kt0 > ktmax) return;
  const int kt1 = min(ktmax, kt0 + chunkKT - 1);

  __shared__ ushort Pls[4][32][72];        // per-wave P [qrow-local][t-local]

  const int tid = threadIdx.x;
  const int wave = tid >> 6, lane = tid & 63;
  const int quad = lane >> 4, l16 = lane & 15;

  // Q fragments (A-layout), 32 rows per wave
  bf16x8 qf[2][4];
  for (int mi = 0; mi < 2; mi++) {
    const ushort* qp = Q + (size_t)(b * T_SEQ + qt * 128 + wave * 32 + mi * 16 + l16) * D_DIM + quad * 8;
    for (int kk = 0; kk < 4; kk++) qf[mi][kk] = ld_frag(qp + kk * 32);
  }

  bf16x8 ones;
  for (int j = 0; j < 8; j++) ones[j] = (short)0x3F80;  // bf16 1.0

  f32x4 o_acc[2][8] = {};
  f32x4 lacc[2] = {};
  const float scale2 = 0.08838834764831845f * 1.4426950408889634f;  // 1/sqrt(128)*log2(e)

  const ushort* Kpb = Kp + (size_t)b * 256 * 4 * 512;
  const ushort* Vpb = Vp + (size_t)b * 8 * 128 * 512;

  for (int kt = kt0; kt <= kt1; kt++) {
    // ---- QK^T ----
    bf16x8 kf[16];
#pragma unroll
    for (int kk = 0; kk < 4; kk++)
#pragma unroll
      for (int ni = 0; ni < 4; ni++)
        kf[kk * 4 + ni] = ld_frag(Kpb + (size_t)((kt * 4 + ni) * 4 + kk) * 512 + lane * 8);
    f32x4 s[2][4] = {};
#pragma unroll
    for (int kk = 0; kk < 4; kk++)
#pragma unroll
      for (int ni = 0; ni < 4; ni++) {
        s[0][ni] = __builtin_amdgcn_mfma_f32_16x16x32_bf16(qf[0][kk], kf[kk * 4 + ni], s[0][ni], 0, 0, 0);
        s[1][ni] = __builtin_amdgcn_mfma_f32_16x16x32_bf16(qf[1][kk], kf[kk * 4 + ni], s[1][ni], 0, 0, 0);
      }
    // ---- p = exp2(s*scale2 - SHIFT), causal mask on diagonal tiles ----
    if (kt >= qt * 2) {
#pragma unroll
      for (int mi = 0; mi < 2; mi++)
#pragma unroll
        for (int ni = 0; ni < 4; ni++) {
          int kidx = kt * 64 + ni * 16 + l16;
#pragma unroll
          for (int r = 0; r < 4; r++) {
            int qidx = qt * 128 + wave * 32 + mi * 16 + quad * 4 + r;
            float v = (kidx > qidx) ? -1e30f : (s[mi][ni][r] * scale2 - SM_SHIFT);
            s[mi][ni][r] = exp2f(v);
          }
        }
    } else {
#pragma unroll
      for (int mi = 0; mi < 2; mi++)
#pragma unroll
        for (int ni = 0; ni < 4; ni++)
#pragma unroll
          for (int r = 0; r < 4; r++)
            s[mi][ni][r] = exp2f(s[mi][ni][r] * scale2 - SM_SHIFT);
    }
    // ---- P -> per-wave LDS (C-layout scatter; wave-internal ordering only) ----
#pragma unroll
    for (int mi = 0; mi < 2; mi++)
#pragma unroll
      for (int ni = 0; ni < 4; ni++)
#pragma unroll
        for (int r = 0; r < 4; r++)
          Pls[wave][mi * 16 + quad * 4 + r][ni * 16 + l16] = f2bf(s[mi][ni][r]);
    // ---- PV ----
    bf16x8 vf[16];
#pragma unroll
    for (int kk2 = 0; kk2 < 2; kk2++)
#pragma unroll
      for (int ni = 0; ni < 8; ni++)
        vf[kk2 * 8 + ni] = ld_frag(Vpb + (size_t)(ni * 128 + kt * 2 + kk2) * 512 + lane * 8);
#pragma unroll
    for (int kk2 = 0; kk2 < 2; kk2++) {
      bf16x8 pf[2];
      pf[0] = *(const bf16x8*)(&Pls[wave][l16][kk2 * 32 + quad * 8]);
      pf[1] = *(const bf16x8*)(&Pls[wave][16 + l16][kk2 * 32 + quad * 8]);
#pragma unroll
      for (int ni = 0; ni < 8; ni++) {
        o_acc[0][ni] = __builtin_amdgcn_mfma_f32_16x16x32_bf16(pf[0], vf[kk2 * 8 + ni], o_acc[0][ni], 0, 0, 0);
        o_acc[1][ni] = __builtin_amdgcn_mfma_f32_16x16x32_bf16(pf[1], vf[kk2 * 8 + ni], o_acc[1][ni], 0, 0, 0);
      }
      lacc[0] = __builtin_amdgcn_mfma_f32_16x16x32_bf16(pf[0], ones, lacc[0], 0, 0, 0);
      lacc[1] = __builtin_amdgcn_mfma_f32_16x16x32_bf16(pf[1], ones, lacc[1], 0, 0, 0);
    }
  }

  // un-normalized partials (directly summable thanks to fixed shift)
  const int slot = (b * 32 + qt) * nchunk + cq;
  for (int mi = 0; mi < 2; mi++)
    for (int ni = 0; ni < 8; ni++)
      for (int r = 0; r < 4; r++) {
        int row = wave * 32 + mi * 16 + quad * 4 + r;
        Po[(size_t)slot * 16384 + row * D_DIM + ni * 16 + l16] = f2bf(o_acc[mi][ni][r]);
      }
  if (l16 == 0)
    for (int mi = 0; mi < 2; mi++)
      for (int r = 0; r < 4; r++) {
        int row = wave * 32 + mi * 16 + quad * 4 + r;
        Ll[slot * 128 + row] = lacc[mi][r];
      }
}

// ============ kernel 6: split-K reduce (plain sums) ============
// grid (32, 4); thread: 1 q-row x 64 cols
__global__ __launch_bounds__(256) void attn_reduce(const ushort* __restrict__ Po,
                                                   const float* __restrict__ Ll,
                                                   float* __restrict__ out,
                                                   int chunkKT, int nchunk) {
  const int qt = blockIdx.x, b = blockIdx.y;
  const int nc = (qt * 2 + 1) / chunkKT + 1;
  const int tid = threadIdx.x;
  const int row = tid >> 1;
  const int c0  = (tid & 1) * 64;
  const int base_slot = (b * 32 + qt) * nchunk;

  float L = 0.f;
  for (int c = 0; c < nc; c++) L += Ll[(base_slot + c) * 128 + row];
  const float inv = 1.0f / L;

  const size_t orow = (size_t)(b * T_SEQ + qt * 128 + row) * D_DIM;
  for (int cc = 0; cc < 64; cc += 8) {
    float a[8] = {0,0,0,0,0,0,0,0};
    for (int c = 0; c < nc; c++) {
      const ushort* p = Po + (size_t)(base_slot + c) * 16384 + row * D_DIM + c0 + cc;
      ushort u[8];
      *(uint4*)u = *(const uint4*)p;
      for (int j = 0; j < 8; j++) a[j] += bf2f(u[j]);
    }
    float4 o0, o1;
    o0.x = a[0] * inv; o0.y = a[1] * inv; o0.z = a[2] * inv; o0.w = a[3] * inv;
    o1.x = a[4] * inv; o1.y = a[5] * inv; o1.z = a[6] * inv; o1.w = a[7] * inv;
    *(float4*)(out + orow + c0 + cc)     = o0;
    *(float4*)(out + orow + c0 + cc + 4) = o1;
  }
}

extern "C" void kernel_launch(void* const* d_in, const int* in_sizes, int n_in,
                              void* d_out, int out_size, void* d_ws, size_t ws_size,
                              hipStream_t stream) {
  const float* x  = (const float*)d_in[0];
  const float* Wq = (const float*)d_in[1];
  const float* Wk = (const float*)d_in[2];
  const float* Wv = (const float*)d_in[3];
  float* out = (float*)d_out;

  // fixed buffers (bf16 elems): Q/K/V 2M each, Wtp 768K, Kp 2M, Vp 2M
  const size_t nQKV = (size_t)M_TOT * D_DIM;
  ushort* Q   = (ushort*)d_ws;
  ushort* Kb  = Q   + nQKV;
  ushort* Vb  = Kb  + nQKV;
  ushort* Wtp = Vb  + nQKV;
  ushort* Kp  = Wtp + (size_t)384 * E_DIM;
  ushort* Vp  = Kp  + nQKV;
  ushort* Po  = Vp  + nQKV;

  // split-K width by available scratch
  size_t fixed_bytes = ((size_t)5 * nQKV + (size_t)384 * E_DIM) * 2;
  size_t per_chunk   = (size_t)NB * 32 * (16384 * 2 + 128 * 4);
  int nchunk = 8;
  while (nchunk > 2 && fixed_bytes + (size_t)nchunk * per_chunk > ws_size) nchunk >>= 1;
  const int chunkKT = 64 / nchunk;
  float* Ll = (float*)(Po + (size_t)NB * 32 * nchunk * 16384);

  hipLaunchKernelGGL(build_wtp,    dim3(32, 2, 3),        dim3(256), 0, stream, Wq, Wk, Wv, Wtp);
  hipLaunchKernelGGL(qkv_gemm,     dim3(256, 2),          dim3(256), 0, stream, x, Wtp, Q, Kb, Vb);
  hipLaunchKernelGGL(k_pack,       dim3(64, NB),          dim3(256), 0, stream, Kb, Kp);
  hipLaunchKernelGGL(v_pack,       dim3(64, NB),          dim3(256), 0, stream, Vb, Vp);
  hipLaunchKernelGGL(attn_partial, dim3(32, nchunk, NB),  dim3(256), 0, stream, Q, Kp, Vp, Po, Ll, chunkKT, nchunk);
  hipLaunchKernelGGL(attn_reduce,  dim3(32, NB),          dim3(256), 0, stream, Po, Ll, out, chunkKT, nchunk);
}